// Round 2
// baseline (999.353 us; speedup 1.0000x reference)
//
#include <hip/hip_runtime.h>
#include <cstdint>
#include <cstddef>

#define T_TOK 8192
#define E_NUM 8
#define D_DIM 1024
#define H_DIM 4096
#define MAXTILES 136
#define TILE 128
#define BK 32

typedef __attribute__((ext_vector_type(8))) short short8;
typedef __attribute__((ext_vector_type(4))) float f32x4;
typedef __attribute__((ext_vector_type(8))) unsigned short ushort8v;
typedef __attribute__((ext_vector_type(4))) unsigned short ushort4v;

__device__ __forceinline__ unsigned short f2b(float f) {
  unsigned int u = __float_as_uint(f);
  u += 0x7fffu + ((u >> 16) & 1u);   // round-to-nearest-even
  return (unsigned short)(u >> 16);
}

__device__ __forceinline__ void async16(const void* g, void* l) {
  __builtin_amdgcn_global_load_lds((const __attribute__((address_space(1))) void*)g,
                                   (__attribute__((address_space(3))) void*)l, 16, 0, 0);
}

// ---------------- router: noisy top-2 + sparse softmax gates ----------------
__global__ void router_kernel(const float* __restrict__ logits, const float* __restrict__ noise,
                              int* __restrict__ counts, int* __restrict__ ti, float* __restrict__ tg) {
  int tk = blockIdx.x * blockDim.x + threadIdx.x;
  if (tk >= T_TOK) return;
  float nz[E_NUM];
#pragma unroll
  for (int e = 0; e < E_NUM; ++e) {
    float l = logits[tk * E_NUM + e];
    float sp = fmaxf(l, 0.f) + log1pf(expf(-fabsf(l)));  // stable softplus
    nz[e] = l + noise[tk * E_NUM + e] * sp;
  }
  int i1 = 0; float v1 = nz[0];
#pragma unroll
  for (int e = 1; e < E_NUM; ++e) if (nz[e] > v1) { v1 = nz[e]; i1 = e; }
  int i2 = -1; float v2 = -3.0e38f;
#pragma unroll
  for (int e = 0; e < E_NUM; ++e) if (e != i1 && nz[e] > v2) { v2 = nz[e]; i2 = e; }
  float ex = expf(v2 - v1);           // <= 1
  float g1 = 1.f / (1.f + ex);
  float g2 = ex / (1.f + ex);
  int s1 = atomicAdd(&counts[i1], 1);
  int s2 = atomicAdd(&counts[i2], 1);
  ti[tk*4+0] = i1; ti[tk*4+1] = s1; ti[tk*4+2] = i2; ti[tk*4+3] = s2;
  tg[tk*2+0] = g1; tg[tk*2+1] = g2;
}

// ---------------- offsets + M-tile table ----------------
__global__ void setup_kernel(const int* __restrict__ counts, int* __restrict__ offs,
                             int* __restrict__ tab) {
  int o = 0;
  for (int e = 0; e < E_NUM; ++e) { offs[e] = o; o += counts[e]; }
  offs[E_NUM] = o;
  int mt = 0;
  for (int e = 0; e < E_NUM; ++e)
    for (int m0 = 0; m0 < counts[e]; m0 += TILE) { tab[mt*2] = e; tab[mt*2+1] = m0; ++mt; }
  for (; mt < MAXTILES; ++mt) { tab[mt*2] = -1; tab[mt*2+1] = 0; }
}

// ---------------- gather x rows into expert-sorted bf16 ----------------
__global__ void gather_kernel(const float* __restrict__ x, const int* __restrict__ ti,
                              const float* __restrict__ tg, const int* __restrict__ offs,
                              unsigned short* __restrict__ xg, int* __restrict__ stok,
                              float* __restrict__ sg) {
  const int tk = blockIdx.x, t = threadIdx.x;
  const int i1 = ti[tk*4+0], s1 = ti[tk*4+1], i2 = ti[tk*4+2], s2 = ti[tk*4+3];
  const int r1 = offs[i1] + s1, r2 = offs[i2] + s2;
  if (t == 0) {
    stok[r1] = tk; sg[r1] = tg[tk*2+0];
    stok[r2] = tk; sg[r2] = tg[tk*2+1];
  }
  const float4 v = *(const float4*)(x + (size_t)tk * D_DIM + t * 4);
  ushort4v bb; bb.x = f2b(v.x); bb.y = f2b(v.y); bb.z = f2b(v.z); bb.w = f2b(v.w);
  *(ushort4v*)(xg + (size_t)r1 * D_DIM + t * 4) = bb;
  *(ushort4v*)(xg + (size_t)r2 * D_DIM + t * 4) = bb;
}

// ---------------- fp32 [K][N] -> bf16 [N][K] transpose (per expert slice) ----------------
__global__ void transpose_kernel(const float* __restrict__ W, unsigned short* __restrict__ Wt,
                                 int K, int N) {
  const int e = blockIdx.z;
  const float* We = W + (size_t)e * K * N;
  unsigned short* Wte = Wt + (size_t)e * K * N;
  __shared__ __align__(16) unsigned short tb[64 * 72];   // [n][k], pad 72 (144B row, 16B-aligned)
  const int n0 = blockIdx.x * 64, k0 = blockIdx.y * 64;
  const int t = threadIdx.x;
  const int kr = t >> 4;            // 0..15
  const int c4 = (t & 15) * 4;      // 0..60
#pragma unroll
  for (int rr = 0; rr < 4; ++rr) {
    int k = kr + rr * 16;
    const float4 v = *(const float4*)(We + (size_t)(k0 + k) * N + n0 + c4);
    tb[(c4+0)*72 + k] = f2b(v.x);
    tb[(c4+1)*72 + k] = f2b(v.y);
    tb[(c4+2)*72 + k] = f2b(v.z);
    tb[(c4+3)*72 + k] = f2b(v.w);
  }
  __syncthreads();
  const int n = t >> 2, kq = (t & 3) * 16;
  ushort8v a = *(const ushort8v*)&tb[n*72 + kq];
  ushort8v b = *(const ushort8v*)&tb[n*72 + kq + 8];
  *(ushort8v*)(Wte + (size_t)(n0+n)*K + k0 + kq) = a;
  *(ushort8v*)(Wte + (size_t)(n0+n)*K + k0 + kq + 8) = b;
}

// ---------------- grouped GEMM, B^T bf16, 128x128 tile, async LDS staging ----------------
// 1-D grid, XCD-swizzled: NB = NX*MAXTILES blocks; c=bid&7 is the XCD slot
// (round-robin dispatch), each XCD works G=NX/8 n-panels with m-tiles outer
// so its B working set (G*256KB) + current A-tiles stay L2-resident.
// LDS chunk layout XOR-swizzled: LDS chunk (row,kc) holds global chunk
// (row, kc^(row&3)) -> ds_read_b128 fragment reads spread over all 32 banks
// (2-way aliasing = free) instead of 8-way conflicts.
// EPI 0: Hout[seg+m][N] = bf16(relu(acc + bias))     (h = GEMM1 output)
// EPI 1: atomicAdd(Out[tok[m]][n], (acc + bias) * gate[m])
template<int EPI, int NX>
__global__ __launch_bounds__(256)
void gemm_bt(const unsigned short* __restrict__ A, const unsigned short* __restrict__ Bt,
             const int K, const int N,
             const int* __restrict__ counts, const int* __restrict__ offs,
             const int* __restrict__ tab,
             const float* __restrict__ bias,
             unsigned short* __restrict__ Hout,
             float* __restrict__ Out,
             const int* __restrict__ slot_tok, const float* __restrict__ slot_gate) {
  constexpr int G = NX / 8;                 // n-panels per XCD
  const int bid = blockIdx.x;
  const int c = bid & 7;                    // XCD slot (dispatch is round-robin)
  const int s = bid >> 3;
  const int xi = c * G + (s % G);           // n-tile: panels cycle inner -> A-tile reuse
  const int mt = s / G;                     // m-tile: outer -> panel stays hot across expert

  const int e = tab[mt*2];
  if (e < 0) return;
  const int m0  = tab[mt*2+1];
  const int cnt = counts[e];
  const int seg = offs[e];
  const int n0  = xi * TILE;

  __shared__ __align__(16) short As[TILE*BK];   // [row][k-chunks xor-swizzled] 8KB
  __shared__ __align__(16) short Bs[TILE*BK];   // [n][k-chunks xor-swizzled]  8KB
  __shared__ int   s_tok[TILE];
  __shared__ float s_g[TILE];

  const int t = threadIdx.x;
  const int lane = t & 63;
  const int wv = t >> 6;
  const int wm = wv & 1, wn = wv >> 1;
  const int fr = lane & 15, fq = lane >> 4;

  if (EPI == 1 && t < TILE) {
    int rl = m0 + t;
    if (rl < cnt) { s_tok[t] = slot_tok[seg + rl]; s_g[t] = slot_gate[seg + rl]; }
    else          { s_tok[t] = 0;                  s_g[t] = 0.f; }
  }

  const unsigned short* Ae = A + (size_t)seg * K;
  const unsigned short* Be = Bt + (size_t)e * N * K + (size_t)n0 * K;

  // staging map: chunk index = t -> row = t>>2, LDS kc = t&3, global kc = (t&3)^(row&3)
  const int row0 = t >> 2;
  const int kcg  = ((t & 3) ^ (row0 & 3)) * 8;   // global k-chunk offset in shorts
  int ar0 = m0 + row0;        ar0 = ar0 < cnt ? ar0 : cnt - 1;
  int ar1 = m0 + row0 + 64;   ar1 = ar1 < cnt ? ar1 : cnt - 1;
  const unsigned short* gA0 = Ae + (size_t)ar0 * K + kcg;
  const unsigned short* gA1 = Ae + (size_t)ar1 * K + kcg;
  const unsigned short* gB0 = Be + (size_t)row0 * K + kcg;
  const unsigned short* gB1 = Be + (size_t)(row0 + 64) * K + kcg;
  char* lA0 = (char*)As + wv*1024;
  char* lA1 = (char*)As + 4096 + wv*1024;
  char* lB0 = (char*)Bs + wv*1024;
  char* lB1 = (char*)Bs + 4096 + wv*1024;

  f32x4 acc[4][4];
#pragma unroll
  for (int i = 0; i < 4; ++i)
#pragma unroll
    for (int j = 0; j < 4; ++j) acc[i][j] = (f32x4){0.f, 0.f, 0.f, 0.f};

  for (int k0 = 0; k0 < K; k0 += BK) {
    async16(gA0, lA0); async16(gA1, lA1);
    async16(gB0, lB0); async16(gB1, lB1);
    gA0 += BK; gA1 += BK; gB0 += BK; gB1 += BK;
    asm volatile("s_waitcnt vmcnt(0)" ::: "memory");
    __syncthreads();

    short8 af[4], bf[4];
#pragma unroll
    for (int i = 0; i < 4; ++i) {
      int row = wm*64 + i*16 + fr;
      af[i] = *(const short8*)&As[row*BK + (fq ^ (row & 3))*8];
    }
#pragma unroll
    for (int j = 0; j < 4; ++j) {
      int row = wn*64 + j*16 + fr;
      bf[j] = *(const short8*)&Bs[row*BK + (fq ^ (row & 3))*8];
    }
#pragma unroll
    for (int i = 0; i < 4; ++i)
#pragma unroll
      for (int j = 0; j < 4; ++j)
        acc[i][j] = __builtin_amdgcn_mfma_f32_16x16x32_bf16(af[i], bf[j], acc[i][j], 0, 0, 0);
    __syncthreads();
  }

  if (EPI == 0) {
    const float* be = bias + (size_t)e * N;
#pragma unroll
    for (int j = 0; j < 4; ++j) {
      int col = n0 + wn*64 + j*16 + fr;
      float bv = be[col];
#pragma unroll
      for (int i = 0; i < 4; ++i) {
        int rb = m0 + wm*64 + i*16 + fq*4;   // expert-local row
#pragma unroll
        for (int r = 0; r < 4; ++r) {
          int rl = rb + r;
          if (rl < cnt) {
            float v = acc[i][j][r] + bv;
            v = v > 0.f ? v : 0.f;
            Hout[(size_t)(seg + rl) * N + col] = f2b(v);
          }
        }
      }
    }
  } else {
    const float* be = bias + (size_t)e * N;
#pragma unroll
    for (int j = 0; j < 4; ++j) {
      int col = n0 + wn*64 + j*16 + fr;
      float bv = be[col];
#pragma unroll
      for (int i = 0; i < 4; ++i) {
        int rbt = wm*64 + i*16 + fq*4;        // tile-local row
#pragma unroll
        for (int r = 0; r < 4; ++r) {
          int rlt = rbt + r;
          if (m0 + rlt < cnt) {
            float v = (acc[i][j][r] + bv) * s_g[rlt];
            unsafeAtomicAdd(Out + (size_t)s_tok[rlt] * N + col, v);
          }
        }
      }
    }
  }
}

extern "C" void kernel_launch(void* const* d_in, const int* in_sizes, int n_in,
                              void* d_out, int out_size, void* d_ws, size_t ws_size,
                              hipStream_t stream) {
  const float* x      = (const float*)d_in[0];
  const float* logits = (const float*)d_in[1];
  const float* noise  = (const float*)d_in[2];
  const float* W1     = (const float*)d_in[3];
  const float* b1     = (const float*)d_in[4];
  const float* W2     = (const float*)d_in[5];
  const float* b2     = (const float*)d_in[6];
  float* out = (float*)d_out;

  char* ws = (char*)d_ws;
  size_t off = 0;
  auto alloc = [&](size_t b) { size_t o = off; off = (off + b + 255) & ~(size_t)255; return o; };
  size_t o_counts = alloc(E_NUM * 4);
  size_t o_offs   = alloc((E_NUM + 1) * 4);
  size_t o_tab    = alloc((size_t)MAXTILES * 2 * 4);
  size_t o_ti     = alloc((size_t)T_TOK * 4 * 4);
  size_t o_tg     = alloc((size_t)T_TOK * 2 * 4);
  size_t o_stok   = alloc((size_t)2 * T_TOK * 4);
  size_t o_sg     = alloc((size_t)2 * T_TOK * 4);
  size_t o_xg     = alloc((size_t)2 * T_TOK * D_DIM * 2);
  size_t o_w1t    = alloc((size_t)E_NUM * D_DIM * H_DIM * 2);
  size_t o_w2t    = alloc((size_t)E_NUM * D_DIM * H_DIM * 2);
  size_t o_h      = alloc((size_t)2 * T_TOK * H_DIM * 2);
  if (off > ws_size) return;   // ws tier too small — will show as clean validation failure

  int*            counts = (int*)(ws + o_counts);
  int*            offsp  = (int*)(ws + o_offs);
  int*            tab    = (int*)(ws + o_tab);
  int*            ti     = (int*)(ws + o_ti);
  float*          tg     = (float*)(ws + o_tg);
  int*            stok   = (int*)(ws + o_stok);
  float*          sg     = (float*)(ws + o_sg);
  unsigned short* xg     = (unsigned short*)(ws + o_xg);
  unsigned short* w1t    = (unsigned short*)(ws + o_w1t);
  unsigned short* w2t    = (unsigned short*)(ws + o_w2t);
  unsigned short* h      = (unsigned short*)(ws + o_h);

  hipMemsetAsync(out, 0, (size_t)out_size * sizeof(float), stream);
  hipMemsetAsync(counts, 0, E_NUM * sizeof(int), stream);

  router_kernel<<<T_TOK / 256, 256, 0, stream>>>(logits, noise, counts, ti, tg);
  setup_kernel<<<1, 1, 0, stream>>>(counts, offsp, tab);
  gather_kernel<<<T_TOK, 256, 0, stream>>>(x, ti, tg, offsp, xg, stok, sg);

  transpose_kernel<<<dim3(H_DIM/64, D_DIM/64, E_NUM), 256, 0, stream>>>(W1, w1t, D_DIM, H_DIM);
  transpose_kernel<<<dim3(D_DIM/64, H_DIM/64, E_NUM), 256, 0, stream>>>(W2, w2t, H_DIM, D_DIM);

  gemm_bt<0, H_DIM/TILE><<<dim3((H_DIM/TILE) * MAXTILES), 256, 0, stream>>>(
      xg, w1t, D_DIM, H_DIM, counts, offsp, tab, b1, h, nullptr, nullptr, nullptr);
  gemm_bt<1, D_DIM/TILE><<<dim3((D_DIM/TILE) * MAXTILES), 256, 0, stream>>>(
      h, w2t, H_DIM, D_DIM, counts, offsp, tab, b2, nullptr, out, stok, sg);
}

// Round 3
// 932.260 us; speedup vs baseline: 1.0720x; 1.0720x over previous
//
#include <hip/hip_runtime.h>
#include <cstdint>
#include <cstddef>

#define T_TOK 8192
#define E_NUM 8
#define D_DIM 1024
#define H_DIM 4096
#define MAXTILES 136
#define TILE 128
#define BK 32
#define STAGES 3

typedef __attribute__((ext_vector_type(8))) short short8;
typedef __attribute__((ext_vector_type(4))) float f32x4;
typedef __attribute__((ext_vector_type(8))) unsigned short ushort8v;
typedef __attribute__((ext_vector_type(4))) unsigned short ushort4v;

__device__ __forceinline__ unsigned short f2b(float f) {
  unsigned int u = __float_as_uint(f);
  u += 0x7fffu + ((u >> 16) & 1u);   // round-to-nearest-even
  return (unsigned short)(u >> 16);
}

__device__ __forceinline__ void async16(const void* g, void* l) {
  __builtin_amdgcn_global_load_lds((const __attribute__((address_space(1))) void*)g,
                                   (__attribute__((address_space(3))) void*)l, 16, 0, 0);
}

// ---------------- router: noisy top-2 + sparse softmax gates ----------------
__global__ void router_kernel(const float* __restrict__ logits, const float* __restrict__ noise,
                              int* __restrict__ counts, int* __restrict__ ti, float* __restrict__ tg) {
  int tk = blockIdx.x * blockDim.x + threadIdx.x;
  if (tk >= T_TOK) return;
  float nz[E_NUM];
#pragma unroll
  for (int e = 0; e < E_NUM; ++e) {
    float l = logits[tk * E_NUM + e];
    float sp = fmaxf(l, 0.f) + log1pf(expf(-fabsf(l)));  // stable softplus
    nz[e] = l + noise[tk * E_NUM + e] * sp;
  }
  int i1 = 0; float v1 = nz[0];
#pragma unroll
  for (int e = 1; e < E_NUM; ++e) if (nz[e] > v1) { v1 = nz[e]; i1 = e; }
  int i2 = -1; float v2 = -3.0e38f;
#pragma unroll
  for (int e = 0; e < E_NUM; ++e) if (e != i1 && nz[e] > v2) { v2 = nz[e]; i2 = e; }
  float ex = expf(v2 - v1);           // <= 1
  float g1 = 1.f / (1.f + ex);
  float g2 = ex / (1.f + ex);
  int s1 = atomicAdd(&counts[i1], 1);
  int s2 = atomicAdd(&counts[i2], 1);
  ti[tk*4+0] = i1; ti[tk*4+1] = s1; ti[tk*4+2] = i2; ti[tk*4+3] = s2;
  tg[tk*2+0] = g1; tg[tk*2+1] = g2;
}

// ---------------- offsets + M-tile table ----------------
__global__ void setup_kernel(const int* __restrict__ counts, int* __restrict__ offs,
                             int* __restrict__ tab) {
  int o = 0;
  for (int e = 0; e < E_NUM; ++e) { offs[e] = o; o += counts[e]; }
  offs[E_NUM] = o;
  int mt = 0;
  for (int e = 0; e < E_NUM; ++e)
    for (int m0 = 0; m0 < counts[e]; m0 += TILE) { tab[mt*2] = e; tab[mt*2+1] = m0; ++mt; }
  for (; mt < MAXTILES; ++mt) { tab[mt*2] = -1; tab[mt*2+1] = 0; }
}

// ---------------- gather x rows into expert-sorted bf16 ----------------
__global__ void gather_kernel(const float* __restrict__ x, const int* __restrict__ ti,
                              const float* __restrict__ tg, const int* __restrict__ offs,
                              unsigned short* __restrict__ xg, int* __restrict__ stok,
                              float* __restrict__ sg) {
  const int tk = blockIdx.x, t = threadIdx.x;
  const int i1 = ti[tk*4+0], s1 = ti[tk*4+1], i2 = ti[tk*4+2], s2 = ti[tk*4+3];
  const int r1 = offs[i1] + s1, r2 = offs[i2] + s2;
  if (t == 0) {
    stok[r1] = tk; sg[r1] = tg[tk*2+0];
    stok[r2] = tk; sg[r2] = tg[tk*2+1];
  }
  const float4 v = *(const float4*)(x + (size_t)tk * D_DIM + t * 4);
  ushort4v bb; bb.x = f2b(v.x); bb.y = f2b(v.y); bb.z = f2b(v.z); bb.w = f2b(v.w);
  *(ushort4v*)(xg + (size_t)r1 * D_DIM + t * 4) = bb;
  *(ushort4v*)(xg + (size_t)r2 * D_DIM + t * 4) = bb;
}

// ---------------- fp32 [K][N] -> bf16 [N][K] transpose (per expert slice) ----------------
__global__ void transpose_kernel(const float* __restrict__ W, unsigned short* __restrict__ Wt,
                                 int K, int N) {
  const int e = blockIdx.z;
  const float* We = W + (size_t)e * K * N;
  unsigned short* Wte = Wt + (size_t)e * K * N;
  __shared__ __align__(16) unsigned short tb[64 * 72];   // [n][k], pad 72 (144B row, 16B-aligned)
  const int n0 = blockIdx.x * 64, k0 = blockIdx.y * 64;
  const int t = threadIdx.x;
  const int kr = t >> 4;            // 0..15
  const int c4 = (t & 15) * 4;      // 0..60
#pragma unroll
  for (int rr = 0; rr < 4; ++rr) {
    int k = kr + rr * 16;
    const float4 v = *(const float4*)(We + (size_t)(k0 + k) * N + n0 + c4);
    tb[(c4+0)*72 + k] = f2b(v.x);
    tb[(c4+1)*72 + k] = f2b(v.y);
    tb[(c4+2)*72 + k] = f2b(v.z);
    tb[(c4+3)*72 + k] = f2b(v.w);
  }
  __syncthreads();
  const int n = t >> 2, kq = (t & 3) * 16;
  ushort8v a = *(const ushort8v*)&tb[n*72 + kq];
  ushort8v b = *(const ushort8v*)&tb[n*72 + kq + 8];
  *(ushort8v*)(Wte + (size_t)(n0+n)*K + k0 + kq) = a;
  *(ushort8v*)(Wte + (size_t)(n0+n)*K + k0 + kq + 8) = b;
}

// ---------------- grouped GEMM, B^T bf16, 128x128 tile ----------------
// 3-stage software-pipelined K-loop: per iter wait vmcnt(8) (only group k,
// issued 3 iters back, must have landed; 8 newer loads stay in flight),
// raw s_barrier (no compiler vmcnt(0) drain), compute, raw s_barrier,
// issue group k+3 into the stage just freed. Exactly 4 vm-ops per iter so
// the manual vmcnt arithmetic stays exact.
// EPI 0: Hout[seg+m][N] = bf16(relu(acc + bias))     (h = GEMM1 output)
// EPI 1: atomicAdd(Out[tok[m]][n], (acc + bias) * gate[m])
template<int EPI, int NX>
__global__ __launch_bounds__(256)
void gemm_bt(const unsigned short* __restrict__ A, const unsigned short* __restrict__ Bt,
             const int K, const int N,
             const int* __restrict__ counts, const int* __restrict__ offs,
             const int* __restrict__ tab,
             const float* __restrict__ bias,
             unsigned short* __restrict__ Hout,
             float* __restrict__ Out,
             const int* __restrict__ slot_tok, const float* __restrict__ slot_gate) {
  constexpr int G = NX / 8;                 // n-panels per XCD
  const int bid = blockIdx.x;
  const int c = bid & 7;                    // XCD slot (dispatch is round-robin)
  const int s = bid >> 3;
  const int xi = c * G + (s % G);           // n-tile
  const int mt = s / G;                     // m-tile

  const int e = tab[mt*2];
  if (e < 0) return;
  const int m0  = tab[mt*2+1];
  const int cnt = counts[e];
  const int seg = offs[e];
  const int n0  = xi * TILE;

  // stage layout: [stage][ As 8KB | Bs 8KB ]
  __shared__ __align__(16) short smem[STAGES * 2 * TILE * BK];
  __shared__ int   s_tok[TILE];
  __shared__ float s_g[TILE];

  const int t = threadIdx.x;
  const int lane = t & 63;
  const int wv = t >> 6;
  const int wm = wv & 1, wn = wv >> 1;
  const int fr = lane & 15, fq = lane >> 4;

  if (EPI == 1 && t < TILE) {
    int rl = m0 + t;
    if (rl < cnt) { s_tok[t] = slot_tok[seg + rl]; s_g[t] = slot_gate[seg + rl]; }
    else          { s_tok[t] = 0;                  s_g[t] = 0.f; }
  }
  __syncthreads();   // real barrier (with drain) BEFORE prologue issues

  const unsigned short* Ae = A + (size_t)seg * K;
  const unsigned short* Be = Bt + (size_t)e * N * K + (size_t)n0 * K;

  // staging map: chunk index = t -> row = t>>2, LDS kc = t&3, global kc = (t&3)^(row&3)
  const int row0 = t >> 2;
  const int kcg  = ((t & 3) ^ (row0 & 3)) * 8;   // xor-swizzled global k-chunk (shorts)
  int ar0 = m0 + row0;        ar0 = ar0 < cnt ? ar0 : cnt - 1;
  int ar1 = m0 + row0 + 64;   ar1 = ar1 < cnt ? ar1 : cnt - 1;
  const unsigned short* rA0 = Ae + (size_t)ar0 * K + kcg;
  const unsigned short* rA1 = Ae + (size_t)ar1 * K + kcg;
  const unsigned short* rB0 = Be + (size_t)row0 * K + kcg;
  const unsigned short* rB1 = Be + (size_t)(row0 + 64) * K + kcg;
  const int ldsOff = wv * 1024;              // this wave's chunk within A (or B) half

  auto issue = [&](int koff, int soff) {
    char* pA = (char*)smem + soff + ldsOff;
    char* pB = (char*)smem + soff + 8192 + ldsOff;
    async16(rA0 + koff, pA);
    async16(rA1 + koff, pA + 4096);
    async16(rB0 + koff, pB);
    async16(rB1 + koff, pB + 4096);
  };

  f32x4 acc[4][4];
#pragma unroll
  for (int i = 0; i < 4; ++i)
#pragma unroll
    for (int j = 0; j < 4; ++j) acc[i][j] = (f32x4){0.f, 0.f, 0.f, 0.f};

  // prologue: fill the 3 stages (K >= STAGES*BK always here)
  issue(0 * BK, 0 * 16384);
  issue(1 * BK, 1 * 16384);
  issue(2 * BK, 2 * 16384);

  int soff = 0;
  for (int k0 = 0; k0 < K; k0 += BK) {
    asm volatile("s_waitcnt vmcnt(8)" ::: "memory");   // group k landed; k+1,k+2 in flight
    asm volatile("s_barrier" ::: "memory");

    const short* As = (const short*)((const char*)smem + soff);
    const short* Bs = (const short*)((const char*)smem + soff + 8192);
    short8 af[4], bf[4];
#pragma unroll
    for (int i = 0; i < 4; ++i) {
      int row = wm*64 + i*16 + fr;
      af[i] = *(const short8*)&As[row*BK + (fq ^ (row & 3))*8];
    }
#pragma unroll
    for (int j = 0; j < 4; ++j) {
      int row = wn*64 + j*16 + fr;
      bf[j] = *(const short8*)&Bs[row*BK + (fq ^ (row & 3))*8];
    }
#pragma unroll
    for (int i = 0; i < 4; ++i)
#pragma unroll
      for (int j = 0; j < 4; ++j)
        acc[i][j] = __builtin_amdgcn_mfma_f32_16x16x32_bf16(af[i], bf[j], acc[i][j], 0, 0, 0);

    asm volatile("s_barrier" ::: "memory");            // all waves done reading this stage

    int kpre = k0 + STAGES * BK;                       // prefetch 3 ahead (clamped tail refetch
    if (kpre > K - BK) kpre = K - BK;                  //  keeps vmcnt accounting uniform)
    issue(kpre, soff);                                 // reuse the stage just freed
    soff += 16384; if (soff == STAGES * 16384) soff = 0;
  }

  if (EPI == 0) {
    const float* be = bias + (size_t)e * N;
#pragma unroll
    for (int j = 0; j < 4; ++j) {
      int col = n0 + wn*64 + j*16 + fr;
      float bv = be[col];
#pragma unroll
      for (int i = 0; i < 4; ++i) {
        int rb = m0 + wm*64 + i*16 + fq*4;   // expert-local row
#pragma unroll
        for (int r = 0; r < 4; ++r) {
          int rl = rb + r;
          if (rl < cnt) {
            float v = acc[i][j][r] + bv;
            v = v > 0.f ? v : 0.f;
            Hout[(size_t)(seg + rl) * N + col] = f2b(v);
          }
        }
      }
    }
  } else {
    const float* be = bias + (size_t)e * N;
#pragma unroll
    for (int j = 0; j < 4; ++j) {
      int col = n0 + wn*64 + j*16 + fr;
      float bv = be[col];
#pragma unroll
      for (int i = 0; i < 4; ++i) {
        int rbt = wm*64 + i*16 + fq*4;        // tile-local row
#pragma unroll
        for (int r = 0; r < 4; ++r) {
          int rlt = rbt + r;
          if (m0 + rlt < cnt) {
            float v = (acc[i][j][r] + bv) * s_g[rlt];
            unsafeAtomicAdd(Out + (size_t)s_tok[rlt] * N + col, v);
          }
        }
      }
    }
  }
}

extern "C" void kernel_launch(void* const* d_in, const int* in_sizes, int n_in,
                              void* d_out, int out_size, void* d_ws, size_t ws_size,
                              hipStream_t stream) {
  const float* x      = (const float*)d_in[0];
  const float* logits = (const float*)d_in[1];
  const float* noise  = (const float*)d_in[2];
  const float* W1     = (const float*)d_in[3];
  const float* b1     = (const float*)d_in[4];
  const float* W2     = (const float*)d_in[5];
  const float* b2     = (const float*)d_in[6];
  float* out = (float*)d_out;

  char* ws = (char*)d_ws;
  size_t off = 0;
  auto alloc = [&](size_t b) { size_t o = off; off = (off + b + 255) & ~(size_t)255; return o; };
  size_t o_counts = alloc(E_NUM * 4);
  size_t o_offs   = alloc((E_NUM + 1) * 4);
  size_t o_tab    = alloc((size_t)MAXTILES * 2 * 4);
  size_t o_ti     = alloc((size_t)T_TOK * 4 * 4);
  size_t o_tg     = alloc((size_t)T_TOK * 2 * 4);
  size_t o_stok   = alloc((size_t)2 * T_TOK * 4);
  size_t o_sg     = alloc((size_t)2 * T_TOK * 4);
  size_t o_xg     = alloc((size_t)2 * T_TOK * D_DIM * 2);
  size_t o_w1t    = alloc((size_t)E_NUM * D_DIM * H_DIM * 2);
  size_t o_w2t    = alloc((size_t)E_NUM * D_DIM * H_DIM * 2);
  size_t o_h      = alloc((size_t)2 * T_TOK * H_DIM * 2);
  if (off > ws_size) return;   // ws tier too small — will show as clean validation failure

  int*            counts = (int*)(ws + o_counts);
  int*            offsp  = (int*)(ws + o_offs);
  int*            tab    = (int*)(ws + o_tab);
  int*            ti     = (int*)(ws + o_ti);
  float*          tg     = (float*)(ws + o_tg);
  int*            stok   = (int*)(ws + o_stok);
  float*          sg     = (float*)(ws + o_sg);
  unsigned short* xg     = (unsigned short*)(ws + o_xg);
  unsigned short* w1t    = (unsigned short*)(ws + o_w1t);
  unsigned short* w2t    = (unsigned short*)(ws + o_w2t);
  unsigned short* h      = (unsigned short*)(ws + o_h);

  hipMemsetAsync(out, 0, (size_t)out_size * sizeof(float), stream);
  hipMemsetAsync(counts, 0, E_NUM * sizeof(int), stream);

  router_kernel<<<T_TOK / 256, 256, 0, stream>>>(logits, noise, counts, ti, tg);
  setup_kernel<<<1, 1, 0, stream>>>(counts, offsp, tab);
  gather_kernel<<<T_TOK, 256, 0, stream>>>(x, ti, tg, offsp, xg, stok, sg);

  transpose_kernel<<<dim3(H_DIM/64, D_DIM/64, E_NUM), 256, 0, stream>>>(W1, w1t, D_DIM, H_DIM);
  transpose_kernel<<<dim3(D_DIM/64, H_DIM/64, E_NUM), 256, 0, stream>>>(W2, w2t, H_DIM, D_DIM);

  gemm_bt<0, H_DIM/TILE><<<dim3((H_DIM/TILE) * MAXTILES), 256, 0, stream>>>(
      xg, w1t, D_DIM, H_DIM, counts, offsp, tab, b1, h, nullptr, nullptr, nullptr);
  gemm_bt<1, D_DIM/TILE><<<dim3((D_DIM/TILE) * MAXTILES), 256, 0, stream>>>(
      h, w2t, H_DIM, D_DIM, counts, offsp, tab, b2, nullptr, out, stok, sg);
}